// Round 8
// baseline (982.877 us; speedup 1.0000x reference)
//
#include <hip/hip_runtime.h>
#include <stdint.h>

// Problem constants
#define N_ROWS 8192
#define D_DIM  1024
#define M_CENT 20000
#define M_PAD  20224          // 79 * 256
#define M_TILES 79            // 256-wide center tiles
#define Y_DIM  256
#define BM 64                 // rows of X per block (2 blocks/CU geometry)
#define BN 256                // centers per M-iteration (wave tile 64x64)
#define BK 64                 // K-chunk of D
#define NCHUNK 16             // D_DIM / BK
#define MSPLIT 8
#define TILES_PER_SPLIT 10    // ceil(79/8)
#define LDSP_STRIDE 264       // 256 + 8 pad: 33 16B-slots/row == 1 mod 8 -> conflict-free

// LDS layout (R10): Z no longer staged -> bufs are X-only and p is DISJOINT.
//   buf0: [0, 4096)         = X[64][64]
//   buf1: [4096, 8192)      = X[64][64] second stage buffer
//   p   : [8192, 25088)     = P[64][264] (16896) -- no aliasing with bufs:
//                             no phase-1->2 barrier, no tile-boundary dance.
// Total 25088 elem = 50176 B + norms 1280 B = 51456 B -> 2 blocks/CU easily.
#define BUFE 4096             // elements per X stage buffer
#define POFF 8192             // p region start

typedef __attribute__((ext_vector_type(4))) float  f32x4;
typedef __attribute__((ext_vector_type(8))) __bf16 bf16x8;

__device__ __forceinline__ unsigned short f2bf(float f) {
    union { float f; unsigned u; } v; v.f = f;
    unsigned u = v.u;
    u += 0x7FFFu + ((u >> 16) & 1u);   // RNE
    return (unsigned short)(u >> 16);
}

// async global->LDS, 16B per lane. LDS dest must be wave-uniform base + lane*16.
__device__ __forceinline__ void gll16(void* lds, const void* g) {
    __builtin_amdgcn_global_load_lds(
        (const __attribute__((address_space(1))) void*)g,
        (__attribute__((address_space(3))) void*)lds, 16, 0, 0);
}

// cast fp32 rows -> bf16, compute fp32 row sum-of-squares; pad rows -> zeros
__global__ void cast_rows_kernel(const float* __restrict__ src,
                                 unsigned short* __restrict__ dst,
                                 float* __restrict__ sq, int nrows_valid) {
    int row = blockIdx.x;
    int t = threadIdx.x;  // 256 threads, 4 floats each = 1024 = D_DIM
    float s = 0.f;
    if (row < nrows_valid) {
        float4 v = ((const float4*)(src + (size_t)row * D_DIM))[t];
        s = v.x * v.x + v.y * v.y + v.z * v.z + v.w * v.w;
        ushort4 o;
        o.x = f2bf(v.x); o.y = f2bf(v.y); o.z = f2bf(v.z); o.w = f2bf(v.w);
        ((ushort4*)(dst + (size_t)row * D_DIM))[t] = o;
    } else {
        ((ushort4*)(dst + (size_t)row * D_DIM))[t] = make_ushort4(0, 0, 0, 0);
    }
    __shared__ float red[4];
    for (int off = 32; off; off >>= 1) s += __shfl_down(s, off, 64);
    if ((t & 63) == 0) red[t >> 6] = s;
    __syncthreads();
    if (t == 0) sq[row] = red[0] + red[1] + red[2] + red[3];
}

// W [M][Y] fp32 -> WT [Y][M_PAD] bf16, pad rows (centers >= M_CENT) -> 0
__global__ void cast_wT_kernel(const float* __restrict__ w,
                               unsigned short* __restrict__ wT) {
    __shared__ float tile[32][33];
    int k0 = blockIdx.x * 32;   // center dim
    int y0 = blockIdx.y * 32;   // Y dim
    int tx = threadIdx.x & 31;
    int ty = threadIdx.x >> 5;  // 0..7
    #pragma unroll
    for (int i = 0; i < 4; ++i) {
        int k = k0 + ty + i * 8;
        float v = (k < M_CENT) ? w[(size_t)k * Y_DIM + y0 + tx] : 0.f;
        tile[tx][ty + i * 8] = v;     // tile[y_local][k_local]
    }
    __syncthreads();
    #pragma unroll
    for (int i = 0; i < 4; ++i) {
        int yl = ty + i * 8;
        wT[(size_t)(y0 + yl) * M_PAD + k0 + tx] = f2bf(tile[yl][tx]);
    }
}

// ---------------------------------------------------------------------------
// R10 (post-mortems R8/R9: spill is structural to Phase-2/3 peak pressure,
// not "the norm registers" -- R9's norm-to-LDS made it worse.  Revert R9.
// New lever: Z's LDS staging has ZERO reuse -- each wave reads only its own
// 64 of the 256 staged Z rows.  32KB of the 40KB per-chunk stage is pure
// LDS pass-through: 5x the stage ops, 2x the LDS BW, for nothing):
//  - Z b-frags load DIRECT global->reg, TRANSIENT (loaded at chunk top,
//    dead after the chunk's MFMAs -- same 32-reg transient footprint as
//    R8's ds_reads; NOT R3/R4's persistent 64-reg double-buffer).
//    sched_barrier(0) before the loads stops hoisting into the previous
//    chunk's MFMA region (caps pressure); the asm memory clobbers at the
//    barriers stop sinking -> loads issue ~200-400cyc before first use,
//    covering L2 latency; 2-block TLP covers the tail.
//  - STAGE = X only (2 gll16).  vmcnt(10): queue at the wait is
//    [X(kc):2][Z(kc):8][X(kc+1):2] -> <=10 outstanding == X(kc) retired.
//    Compiler's own waits for Z-use are partial (vmcnt(6)-ish), never 0.
//  - p now DISJOINT from bufs (LDS 51.4KB total): phase-1->2 barrier
//    deleted; no aliasing constraints; X-prefetch at chunk15 is trivially
//    legal (X is tile-independent: KBN=0 re-stages chunk-0 X).
//  - Norms: back to the R2 pattern that never spilled -- dedicated LDS
//    arrays, written at block/tile top (one lgkm drain), read as
//    broadcast LDS scalars in Phase 2.  No norm VGPRs anywhere.
//  - launch_bounds(256,2); MSPLIT=8; grid dim3(128,8) (R2 known-good).
//  Sentinels: WRITE ~75-120MB (spill), MfmaUtil 38-45%, LDS ~51.5KB.
// ---------------------------------------------------------------------------

#define STAGE_X(PAR, KBASE) do {                                              \
    _Pragma("unroll")                                                         \
    for (int i_ = 0; i_ < 2; ++i_) {          /* X: 512 16B-chunks */         \
        int lin_ = t + i_ * 256;                                              \
        int row_ = lin_ >> 3, c_ = lin_ & 7;                                  \
        gll16(&lds_all[(PAR) * BUFE + lin_ * 8],                              \
              Xb + (size_t)(row0 + row_) * D_DIM + (KBASE) +                  \
                  ((c_ ^ (row_ & 7)) * 8));                                   \
    } } while (0)

// One K-chunk.  PAR literal 0/1 (static indexing).  KB = this chunk's kbase,
// KBN = next chunk's (0 at tile end: X is tile-independent).
#define CHUNK(PAR, M0, KB, KBN) do {                                          \
    __builtin_amdgcn_sched_barrier(0);     /* no hoist into prev MFMAs */     \
    bf16x8 b8[8];                                                             \
    _Pragma("unroll")                                                         \
    for (int kt_ = 0; kt_ < 2; ++kt_)                                         \
        _Pragma("unroll")                                                     \
        for (int jt_ = 0; jt_ < 4; ++jt_)                                     \
            b8[kt_ * 4 + jt_] = *(const bf16x8*)(Zb +                         \
                (size_t)((M0) + wave * 64 + jt_ * 16 + l16) * D_DIM +         \
                (KB) + kt_ * 32 + quad * 8);                                  \
    asm volatile("" ::: "memory");                                            \
    __builtin_amdgcn_s_barrier();          /* barA: buf[PAR^1] free */        \
    asm volatile("" ::: "memory");                                            \
    STAGE_X(PAR ^ 1, KBN);                                                    \
    __builtin_amdgcn_sched_barrier(0);                                        \
    asm volatile("s_waitcnt vmcnt(10)" ::: "memory"); /* X(kc) landed */      \
    __builtin_amdgcn_s_barrier();          /* barB: everyone's X landed */    \
    asm volatile("" ::: "memory");                                            \
    _Pragma("unroll")                                                         \
    for (int kt_ = 0; kt_ < 2; ++kt_) {                                       \
        const int sw_ = ((kt_ * 4 + quad) ^ cx) * 8;                          \
        bf16x8 a_[4];                                                         \
        _Pragma("unroll")                                                     \
        for (int it_ = 0; it_ < 4; ++it_)                                     \
            a_[it_] = *(const bf16x8*)&lds_all[(PAR) * BUFE +                 \
                (it_ * 16 + l16) * BK + sw_];                                 \
        __builtin_amdgcn_s_setprio(1);                                        \
        _Pragma("unroll")                                                     \
        for (int it_ = 0; it_ < 4; ++it_)                                     \
            _Pragma("unroll")                                                 \
            for (int jt_ = 0; jt_ < 4; ++jt_)                                 \
                S[it_ * 4 + jt_] = __builtin_amdgcn_mfma_f32_16x16x32_bf16(   \
                    a_[it_], b8[kt_ * 4 + jt_], S[it_ * 4 + jt_], 0, 0, 0);   \
        __builtin_amdgcn_s_setprio(0);                                        \
    } } while (0)

__global__ void __launch_bounds__(256, 2)
fused_kernel(const unsigned short* __restrict__ Xb,
             const unsigned short* __restrict__ Zb,
             const unsigned short* __restrict__ WbT,
             const float* __restrict__ xsq,
             const float* __restrict__ zsq,
             const int* __restrict__ bwp,
             float* __restrict__ out) {
    __shared__ unsigned short lds_all[POFF + BM * LDSP_STRIDE];  // 50176 B
    __shared__ float lds_xsq[BM];                                // 256 B
    __shared__ float lds_zsq[BN];                                // 1 KB

    const int t    = threadIdx.x;
    const int wave = t >> 6;      // 0..3: m-slab (phase1 B, phase3 y-slab)
    const int lane = t & 63;
    const int quad = lane >> 4;
    const int l16  = lane & 15;
    const int cx   = l16 & 7;     // row&7 of every frag row this lane touches

    const int row0 = blockIdx.x * BM;          // R2 known-good mapping
    const int mt0  = blockIdx.y * TILES_PER_SPLIT;
    int mt_end = mt0 + TILES_PER_SPLIT;
    if (mt_end > M_TILES) mt_end = M_TILES;

    // bandwidth: int32 per harness convention (Python int 10); tolerate float bits too
    int bwi = *bwp;
    float bw;
    if (bwi > 0 && bwi < 1000000) bw = (float)bwi;
    else { union { int i; float f; } u; u.i = bwi; bw = u.f; }
    const float inv_bw = 1.0f / bw;

    if (t < BM) lds_xsq[t] = xsq[row0 + t];    // once per block (R2 pattern)

    const f32x4 vzero = {0.f, 0.f, 0.f, 0.f};
    f32x4 Oacc[16];
    #pragma unroll
    for (int i = 0; i < 16; ++i) Oacc[i] = vzero;

    // prologue: stage (chunk 0) X -> buf0
    STAGE_X(0, 0);
    __builtin_amdgcn_sched_barrier(0);

    for (int mt = mt0; mt < mt_end; ++mt) {
        const int m0 = mt * BN;

        // zsq -> dedicated LDS (R2's no-spill pattern).  lgkm drain makes the
        // write complete before this wave's next barrier; chunk barriers give
        // cross-wave visibility long before Phase 2 reads it.  (Safe vs the
        // previous tile: all waves passed its Phase-2->3 barrier already.)
        lds_zsq[t] = zsq[m0 + t];              // BN == blockDim.x == 256
        asm volatile("s_waitcnt lgkmcnt(0)" ::: "memory");

        f32x4 S[16];
        #pragma unroll
        for (int i = 0; i < 16; ++i) S[i] = vzero;

        // -------- Phase 1: S[64x256] = X * Z^T over D --------
        // X: LDS double-buffer, counted-vmcnt pipeline (chunk kc reads
        // buf[kc&1], stages kc+1; chunk 15 re-stages chunk-0 X: KBN=0).
        // Z: direct global->reg transient b-frags (no LDS pass-through).
        #pragma unroll 1
        for (int kc = 0; kc < NCHUNK; kc += 2) {
            const bool last = (kc + 2 == NCHUNK);
            CHUNK(0, m0, kc * BK, (kc + 1) * BK);
            CHUNK(1, m0, (kc + 1) * BK, last ? 0 : (kc + 2) * BK);
        }
        // no phase-1->2 barrier needed: p is disjoint from the X bufs.

        // -------- Phase 2: P = exp(-sqrt(d2)/bw) -> p (bf16) --------
        #pragma unroll
        for (int it = 0; it < 4; ++it) {
            #pragma unroll
            for (int jt = 0; jt < 4; ++jt) {
                f32x4 s4 = S[it * 4 + jt];
                const int col = wave * 64 + jt * 16 + l16;
                const float zq = lds_zsq[col];
                #pragma unroll
                for (int r = 0; r < 4; ++r) {
                    const int row = it * 16 + quad * 4 + r;   // C-layout
                    float d2 = lds_xsq[row] + zq - 2.0f * s4[r];
                    d2 = fmaxf(d2, 0.f);
                    float d;
                    asm("v_sqrt_f32 %0, %1" : "=v"(d) : "v"(d2));
                    float p = __expf(-d * inv_bw);
                    lds_all[POFF + row * LDSP_STRIDE + col] = f2bf(p);
                }
            }
        }
        // P-write -> P-read: LDS-only drain; X prefetch stays in flight
        asm volatile("s_waitcnt lgkmcnt(0)" ::: "memory");
        __builtin_amdgcn_s_barrier();
        asm volatile("" ::: "memory");

        // -------- Phase 3: O += P[64x256] * Wtile[256x256] --------
        #pragma unroll
        for (int ks = 0; ks < 8; ++ks) {
            const int koff = ks * 32 + quad * 8;
            bf16x8 a[4], b[4];
            #pragma unroll
            for (int rt = 0; rt < 4; ++rt)
                a[rt] = *(const bf16x8*)&lds_all[POFF +
                    (rt * 16 + l16) * LDSP_STRIDE + koff];
            #pragma unroll
            for (int ct = 0; ct < 4; ++ct) {
                const int y = wave * 64 + ct * 16 + l16;
                b[ct] = *(const bf16x8*)(WbT + (size_t)y * M_PAD + m0 + koff);
            }
            __builtin_amdgcn_s_setprio(1);
            #pragma unroll
            for (int rt = 0; rt < 4; ++rt)
                #pragma unroll
                for (int ct = 0; ct < 4; ++ct)
                    Oacc[rt * 4 + ct] = __builtin_amdgcn_mfma_f32_16x16x32_bf16(
                        a[rt], b[ct], Oacc[rt * 4 + ct], 0, 0, 0);
            __builtin_amdgcn_s_setprio(0);
        }
        // next tile's CHUNK(0) barA separates these p reads from... nothing:
        // p is only rewritten in next Phase 2, 16 chunk-barriers away.
    }

    // drain the dangling last-tile X prefetch before LDS is released
    asm volatile("s_waitcnt vmcnt(0)" ::: "memory");

    // -------- epilogue: accumulate M-splits via device-scope fp32 atomics ----
    #pragma unroll
    for (int rt = 0; rt < 4; ++rt) {
        #pragma unroll
        for (int ct = 0; ct < 4; ++ct) {
            f32x4 v = Oacc[rt * 4 + ct];
            const int y = wave * 64 + ct * 16 + l16;
            #pragma unroll
            for (int r = 0; r < 4; ++r) {
                const int row = row0 + rt * 16 + quad * 4 + r;
                atomicAdd(&out[(size_t)row * Y_DIM + y], v[r]);
            }
        }
    }
}

extern "C" void kernel_launch(void* const* d_in, const int* in_sizes, int n_in,
                              void* d_out, int out_size, void* d_ws, size_t ws_size,
                              hipStream_t stream) {
    const float* X = (const float*)d_in[0];
    const float* Z = (const float*)d_in[1];
    const float* W = (const float*)d_in[2];
    const int*  bw = (const int*)d_in[3];
    float* out = (float*)d_out;

    char* ws = (char*)d_ws;
    size_t off = 0;
    unsigned short* Xb  = (unsigned short*)(ws + off); off += (size_t)N_ROWS * D_DIM * 2;
    unsigned short* Zb  = (unsigned short*)(ws + off); off += (size_t)M_PAD * D_DIM * 2;
    unsigned short* WbT = (unsigned short*)(ws + off); off += (size_t)Y_DIM * M_PAD * 2;
    float* xsq = (float*)(ws + off); off += (size_t)N_ROWS * 4;
    float* zsq = (float*)(ws + off); off += (size_t)M_PAD * 4;
    // total ws use: ~68.7 MB

    hipMemsetAsync(d_out, 0, (size_t)out_size * sizeof(float), stream);
    cast_rows_kernel<<<N_ROWS, 256, 0, stream>>>(X, Xb, xsq, N_ROWS);
    cast_rows_kernel<<<M_PAD, 256, 0, stream>>>(Z, Zb, zsq, M_CENT);
    cast_wT_kernel<<<dim3(M_PAD / 32, Y_DIM / 32), 256, 0, stream>>>(W, WbT);
    fused_kernel<<<dim3(N_ROWS / BM, MSPLIT), 256, 0, stream>>>(
        Xb, Zb, WbT, xsq, zsq, bw, out);
}

// Round 9
// 853.882 us; speedup vs baseline: 1.1511x; 1.1511x over previous
//
#include <hip/hip_runtime.h>
#include <stdint.h>

// Problem constants
#define N_ROWS 8192
#define D_DIM  1024
#define M_CENT 20000
#define M_PAD  20224          // 79 * 256
#define M_TILES 79            // 256-wide center tiles
#define Y_DIM  256
#define BM 64                 // rows of X per block (2 blocks/CU geometry)
#define BN 256                // centers per M-iteration (wave tile 64x64)
#define BK 64                 // K-chunk of D
#define NCHUNK 16             // D_DIM / BK
#define MSPLIT 8
#define TILES_PER_SPLIT 10    // ceil(79/8)
#define LDSP_STRIDE 264       // 256 + 8 pad: 33 16B-slots/row == 1 mod 8 -> conflict-free

// LDS layout (u16 element offsets into lds_all):
//   buf0: [0, 20480)        = X[64][64] (4096) + Z[256][64] (16384)
//   buf1: [20480, 40960)    = same, second stage buffer
//   p   : [20480, 37376)    = P[64][264] (16896) -- aliases buf1 ONLY; buf0
//                             stays free so next-tile chunk-0 prefetch flies
//                             during Phases 2-3.
// Total 40960 elem = 81920 B = EXACTLY half of 160KB -> 2 blocks/CU
// (R7/R8 HW-verified: LDS_Block_Size=81920, Occupancy 22% = 2 blocks/CU).
#define BUFE 20480            // elements per stage buffer
#define ZOFF 4096             // Z offset within a buffer
#define POFF 20480            // p region start (== buf1)

typedef __attribute__((ext_vector_type(4))) float  f32x4;
typedef __attribute__((ext_vector_type(8))) __bf16 bf16x8;

__device__ __forceinline__ unsigned short f2bf(float f) {
    union { float f; unsigned u; } v; v.f = f;
    unsigned u = v.u;
    u += 0x7FFFu + ((u >> 16) & 1u);   // RNE
    return (unsigned short)(u >> 16);
}

// async global->LDS, 16B per lane. LDS dest must be wave-uniform base + lane*16.
__device__ __forceinline__ void gll16(void* lds, const void* g) {
    __builtin_amdgcn_global_load_lds(
        (const __attribute__((address_space(1))) void*)g,
        (__attribute__((address_space(3))) void*)lds, 16, 0, 0);
}

// cast fp32 rows -> bf16, compute fp32 row sum-of-squares; pad rows -> zeros
__global__ void cast_rows_kernel(const float* __restrict__ src,
                                 unsigned short* __restrict__ dst,
                                 float* __restrict__ sq, int nrows_valid) {
    int row = blockIdx.x;
    int t = threadIdx.x;  // 256 threads, 4 floats each = 1024 = D_DIM
    float s = 0.f;
    if (row < nrows_valid) {
        float4 v = ((const float4*)(src + (size_t)row * D_DIM))[t];
        s = v.x * v.x + v.y * v.y + v.z * v.z + v.w * v.w;
        ushort4 o;
        o.x = f2bf(v.x); o.y = f2bf(v.y); o.z = f2bf(v.z); o.w = f2bf(v.w);
        ((ushort4*)(dst + (size_t)row * D_DIM))[t] = o;
    } else {
        ((ushort4*)(dst + (size_t)row * D_DIM))[t] = make_ushort4(0, 0, 0, 0);
    }
    __shared__ float red[4];
    for (int off = 32; off; off >>= 1) s += __shfl_down(s, off, 64);
    if ((t & 63) == 0) red[t >> 6] = s;
    __syncthreads();
    if (t == 0) sq[row] = red[0] + red[1] + red[2] + red[3];
}

// W [M][Y] fp32 -> WT [Y][M_PAD] bf16, pad rows (centers >= M_CENT) -> 0
__global__ void cast_wT_kernel(const float* __restrict__ w,
                               unsigned short* __restrict__ wT) {
    __shared__ float tile[32][33];
    int k0 = blockIdx.x * 32;   // center dim
    int y0 = blockIdx.y * 32;   // Y dim
    int tx = threadIdx.x & 31;
    int ty = threadIdx.x >> 5;  // 0..7
    #pragma unroll
    for (int i = 0; i < 4; ++i) {
        int k = k0 + ty + i * 8;
        float v = (k < M_CENT) ? w[(size_t)k * Y_DIM + y0 + tx] : 0.f;
        tile[tx][ty + i * 8] = v;     // tile[y_local][k_local]
    }
    __syncthreads();
    #pragma unroll
    for (int i = 0; i < 4; ++i) {
        int yl = ty + i * 8;
        wT[(size_t)(y0 + yl) * M_PAD + k0 + tx] = f2bf(tile[yl][tx]);
    }
}

// ---------------------------------------------------------------------------
// R11 = R8 + AGPR pinning (R10 post-mortem: identical S/Oacc structure ran
// spill-free -> R8's 200MB spill is an ALLOCATOR CHOICE, spilling idle-but-
// live accumulator state (Oacc is dead weight through Phases 1-2) instead of
// parking it in AGPRs.  R9/R10 showed load-placement can't steer this; pin
// the register CLASS directly):
//  - asm("" : "+a"(x)) = zero-instruction AGPR class-pin (LLVM AMDGPU "a"
//    constraint; gfx950 MFMA takes AGPR C/D natively).  Pins: Oacc at init
//    and after each Phase 3 (covers the idle Phase-1-2 span + cross-tile);
//    S at each tile's init (seeds the MFMA accumulation chain AGPR-side).
//    With 128 accumulators in AGPR, VGPR side holds only transients (~70
//    peak incl. xq/zq) -> no spill pressure.  Phase-2 S reads become
//    v_accvgpr_read (64/tile, negligible).
//  - R10's other lesson: Z must STAY on the deep global_load_lds pipeline
//    (direct-to-reg Z exposed L2 latency/BW: MfmaUtil 20%, 887us).
//  - Everything else byte-identical to R8 (best, 593us):
//    * R2 geometry: BM=64, 4 waves, MSPLIT=8, 1024 blocks, 2 resident/CU.
//    * Counted-vmcnt raw-barrier pipeline (T3+T4, HW-verified):
//        barA -> STAGE(next buf, 10 gll16) -> s_waitcnt vmcnt(10) -> barB
//        -> ds_read frags -> 32 MFMA; vmcnt never drains to 0 in phase 1;
//      chunk-15 stages next tile's chunk-0 into buf0 (lands in Phases 2-3).
//    * xq/zq loaded at Phase-2 top (Phase-2-only live range).
//    * v_sqrt_f32 inline; launch_bounds(256,2).
//  Sentinels: WRITE ~75MB / FETCH ~450MB = spill dead (primary).
//  Forks: WRITE ~275 -> pins ignored -> fold norms into MFMA (augmented-D);
//  WRITE low but dur >=580 -> spill wasn't critical-path -> ablate phases.
// ---------------------------------------------------------------------------

#define STAGE(PAR, M0, KBASE) do {                                            \
    _Pragma("unroll")                                                         \
    for (int i_ = 0; i_ < 2; ++i_) {          /* X: 512 16B-chunks */         \
        int lin_ = t + i_ * 256;                                              \
        int row_ = lin_ >> 3, c_ = lin_ & 7;                                  \
        gll16(&lds_all[(PAR) * BUFE + lin_ * 8],                              \
              Xb + (size_t)(row0 + row_) * D_DIM + (KBASE) +                  \
                  ((c_ ^ (row_ & 7)) * 8));                                   \
    }                                                                         \
    _Pragma("unroll")                                                         \
    for (int i_ = 0; i_ < 8; ++i_) {          /* Z: 2048 16B-chunks */        \
        int lin_ = t + i_ * 256;                                              \
        int row_ = lin_ >> 3, c_ = lin_ & 7;                                  \
        gll16(&lds_all[(PAR) * BUFE + ZOFF + lin_ * 8],                       \
              Zb + (size_t)((M0) + row_) * D_DIM + (KBASE) +                  \
                  ((c_ ^ (row_ & 7)) * 8));                                   \
    } } while (0)

// One K-chunk.  PAR literal 0/1.  On entry: [stage(kc)x10] outstanding
// (issued one chunk earlier); buf[PAR^1]'s readers all passed barA.
// vmcnt(10) keeps the 10 JUST-ISSUED ops outstanding and drains everything
// older (stage(kc) + any stray scalar loads) -- robust counting.
#define CHUNK(PAR, M0N, KBN) do {                                             \
    asm volatile("" ::: "memory");                                            \
    __builtin_amdgcn_s_barrier();          /* barA: buf[PAR^1] free */        \
    asm volatile("" ::: "memory");                                            \
    STAGE(PAR ^ 1, M0N, KBN);                                                 \
    __builtin_amdgcn_sched_barrier(0);                                        \
    asm volatile("s_waitcnt vmcnt(10)" ::: "memory"); /* stage(kc) done */    \
    __builtin_amdgcn_s_barrier();          /* barB: everyone's stage done */  \
    asm volatile("" ::: "memory");                                            \
    _Pragma("unroll")                                                         \
    for (int kt_ = 0; kt_ < 2; ++kt_) {                                       \
        const int sw_ = ((kt_ * 4 + quad) ^ cx) * 8;                          \
        bf16x8 a_[4], b_[4];                                                  \
        _Pragma("unroll")                                                     \
        for (int it_ = 0; it_ < 4; ++it_)                                     \
            a_[it_] = *(const bf16x8*)&lds_all[(PAR) * BUFE +                 \
                (it_ * 16 + l16) * BK + sw_];                                 \
        _Pragma("unroll")                                                     \
        for (int jt_ = 0; jt_ < 4; ++jt_)                                     \
            b_[jt_] = *(const bf16x8*)&lds_all[(PAR) * BUFE + ZOFF +          \
                (wave * 64 + jt_ * 16 + l16) * BK + sw_];                     \
        __builtin_amdgcn_s_setprio(1);                                        \
        _Pragma("unroll")                                                     \
        for (int it_ = 0; it_ < 4; ++it_)                                     \
            _Pragma("unroll")                                                 \
            for (int jt_ = 0; jt_ < 4; ++jt_)                                 \
                S[it_ * 4 + jt_] = __builtin_amdgcn_mfma_f32_16x16x32_bf16(   \
                    a_[it_], b_[jt_], S[it_ * 4 + jt_], 0, 0, 0);             \
        __builtin_amdgcn_s_setprio(0);                                        \
    } } while (0)

__global__ void __launch_bounds__(256, 2)
fused_kernel(const unsigned short* __restrict__ Xb,
             const unsigned short* __restrict__ Zb,
             const unsigned short* __restrict__ WbT,
             const float* __restrict__ xsq,
             const float* __restrict__ zsq,
             const int* __restrict__ bwp,
             float* __restrict__ out) {
    __shared__ unsigned short lds_all[2 * BUFE];   // EXACTLY 81920 B

    const int t    = threadIdx.x;
    const int wave = t >> 6;      // 0..3: m-slab (phase1 B, phase3 y-slab)
    const int lane = t & 63;
    const int quad = lane >> 4;
    const int l16  = lane & 15;
    const int cx   = l16 & 7;     // row&7 of every frag row this lane touches

    const int row0 = blockIdx.x * BM;          // R2 known-good mapping
    const int mt0  = blockIdx.y * TILES_PER_SPLIT;
    int mt_end = mt0 + TILES_PER_SPLIT;
    if (mt_end > M_TILES) mt_end = M_TILES;

    // bandwidth: int32 per harness convention (Python int 10); tolerate float bits too
    int bwi = *bwp;
    float bw;
    if (bwi > 0 && bwi < 1000000) bw = (float)bwi;
    else { union { int i; float f; } u; u.i = bwi; bw = u.f; }
    const float inv_bw = 1.0f / bw;

    const f32x4 vzero = {0.f, 0.f, 0.f, 0.f};
    f32x4 Oacc[16];
    #pragma unroll
    for (int i = 0; i < 16; ++i) Oacc[i] = vzero;
    // Pin Oacc into AGPRs: parks 64 idle regs out of the VGPR file for the
    // whole Phase-1/2 span (the R8 spill candidate).
    #pragma unroll
    for (int i = 0; i < 16; ++i) asm("" : "+a"(Oacc[i]));

    // prologue: stage (tile mt0, chunk 0) -> buf0
    STAGE(0, mt0 * BN, 0);
    __builtin_amdgcn_sched_barrier(0);

    for (int mt = mt0; mt < mt_end; ++mt) {
        const int m0 = mt * BN;
        // last tile of split prefetches itself (valid mem, unused)
        const int m0next = (mt + 1 < mt_end) ? m0 + BN : m0;

        f32x4 S[16];
        #pragma unroll
        for (int i = 0; i < 16; ++i) S[i] = vzero;
        // Seed the S accumulation chain AGPR-side (MFMA C/D is AGPR-native;
        // coalescing keeps the whole 16-chunk chain there).
        #pragma unroll
        for (int i = 0; i < 16; ++i) asm("" : "+a"(S[i]));

        // -------- Phase 1: S[64x256] = X * Z^T over D, counted-vmcnt pipe --
        // chunk kc reads buf[kc&1]; stages kc+1 into buf[(kc+1)&1].
        // kc=15 stages NEXT TILE's chunk 0 into buf0 (disjoint from p),
        // landing during Phases 2-3 -> no drain at tile boundary.
        #pragma unroll 1
        for (int kc = 0; kc < NCHUNK; kc += 2) {
            const bool last = (kc + 2 == NCHUNK);
            CHUNK(0, m0, (kc + 1) * BK);
            CHUNK(1, last ? m0next : m0, last ? 0 : (kc + 2) * BK);
        }

        // phase1 -> phase2: all buf1 readers done before p overwrites it
        asm volatile("" ::: "memory");
        __builtin_amdgcn_s_barrier();
        asm volatile("" ::: "memory");

        // -------- Phase 2: P = exp(-sqrt(d2)/bw) -> p (bf16) --------
        // xq/zq loaded HERE (L2-hot, once per tile): live range = Phase 2
        // only; VGPR side is accumulator-free (S/Oacc in AGPR) -> no spill.
        f32x4 xq[4];
        #pragma unroll
        for (int it = 0; it < 4; ++it)
            xq[it] = *(const f32x4*)(xsq + row0 + it * 16 + quad * 4);
        float zq[4];
        #pragma unroll
        for (int jt = 0; jt < 4; ++jt)
            zq[jt] = zsq[m0 + wave * 64 + jt * 16 + l16];

        #pragma unroll
        for (int it = 0; it < 4; ++it) {
            #pragma unroll
            for (int jt = 0; jt < 4; ++jt) {
                f32x4 s4 = S[it * 4 + jt];
                const int col = wave * 64 + jt * 16 + l16;
                #pragma unroll
                for (int r = 0; r < 4; ++r) {
                    const int row = it * 16 + quad * 4 + r;   // C-layout
                    float d2 = xq[it][r] + zq[jt] - 2.0f * s4[r];
                    d2 = fmaxf(d2, 0.f);
                    float d;
                    asm("v_sqrt_f32 %0, %1" : "=v"(d) : "v"(d2));
                    float p = __expf(-d * inv_bw);
                    lds_all[POFF + row * LDSP_STRIDE + col] = f2bf(p);
                }
            }
        }
        // P-write -> P-read: LDS-only drain; buf0 prefetch stays in flight
        asm volatile("s_waitcnt lgkmcnt(0)" ::: "memory");
        __builtin_amdgcn_s_barrier();
        asm volatile("" ::: "memory");

        // -------- Phase 3: O += P[64x256] * Wtile[256x256] --------
        #pragma unroll
        for (int ks = 0; ks < 8; ++ks) {
            const int koff = ks * 32 + quad * 8;
            bf16x8 a[4], b[4];
            #pragma unroll
            for (int rt = 0; rt < 4; ++rt)
                a[rt] = *(const bf16x8*)&lds_all[POFF +
                    (rt * 16 + l16) * LDSP_STRIDE + koff];
            #pragma unroll
            for (int ct = 0; ct < 4; ++ct) {
                const int y = wave * 64 + ct * 16 + l16;
                b[ct] = *(const bf16x8*)(WbT + (size_t)y * M_PAD + m0 + koff);
            }
            __builtin_amdgcn_s_setprio(1);
            #pragma unroll
            for (int rt = 0; rt < 4; ++rt)
                #pragma unroll
                for (int ct = 0; ct < 4; ++ct)
                    Oacc[rt * 4 + ct] = __builtin_amdgcn_mfma_f32_16x16x32_bf16(
                        a[rt], b[ct], Oacc[rt * 4 + ct], 0, 0, 0);
            __builtin_amdgcn_s_setprio(0);
        }
        // Re-pin Oacc for the cross-tile / next-Phase-1-2 idle span.
        #pragma unroll
        for (int i = 0; i < 16; ++i) asm("" : "+a"(Oacc[i]));
        // next tile's CHUNK(0) barA separates these p reads from the next
        // stage writes into buf1 (p ds_reads are lgkm-drained pre-MFMA).
    }

    // drain the dangling last-tile prefetch before LDS is released
    asm volatile("s_waitcnt vmcnt(0)" ::: "memory");

    // -------- epilogue: accumulate M-splits via device-scope fp32 atomics ----
    #pragma unroll
    for (int rt = 0; rt < 4; ++rt) {
        #pragma unroll
        for (int ct = 0; ct < 4; ++ct) {
            f32x4 v = Oacc[rt * 4 + ct];
            const int y = wave * 64 + ct * 16 + l16;
            #pragma unroll
            for (int r = 0; r < 4; ++r) {
                const int row = row0 + rt * 16 + quad * 4 + r;
                atomicAdd(&out[(size_t)row * Y_DIM + y], v[r]);
            }
        }
    }
}

extern "C" void kernel_launch(void* const* d_in, const int* in_sizes, int n_in,
                              void* d_out, int out_size, void* d_ws, size_t ws_size,
                              hipStream_t stream) {
    const float* X = (const float*)d_in[0];
    const float* Z = (const float*)d_in[1];
    const float* W = (const float*)d_in[2];
    const int*  bw = (const int*)d_in[3];
    float* out = (float*)d_out;

    char* ws = (char*)d_ws;
    size_t off = 0;
    unsigned short* Xb  = (unsigned short*)(ws + off); off += (size_t)N_ROWS * D_DIM * 2;
    unsigned short* Zb  = (unsigned short*)(ws + off); off += (size_t)M_PAD * D_DIM * 2;
    unsigned short* WbT = (unsigned short*)(ws + off); off += (size_t)Y_DIM * M_PAD * 2;
    float* xsq = (float*)(ws + off); off += (size_t)N_ROWS * 4;
    float* zsq = (float*)(ws + off); off += (size_t)M_PAD * 4;
    // total ws use: ~68.7 MB

    hipMemsetAsync(d_out, 0, (size_t)out_size * sizeof(float), stream);
    cast_rows_kernel<<<N_ROWS, 256, 0, stream>>>(X, Xb, xsq, N_ROWS);
    cast_rows_kernel<<<M_PAD, 256, 0, stream>>>(Z, Zb, zsq, M_CENT);
    cast_wT_kernel<<<dim3(M_PAD / 32, Y_DIM / 32), 256, 0, stream>>>(W, WbT);
    fused_kernel<<<dim3(N_ROWS / BM, MSPLIT), 256, 0, stream>>>(
        Xb, Zb, WbT, xsq, zsq, bw, out);
}

// Round 10
// 783.416 us; speedup vs baseline: 1.2546x; 1.0899x over previous
//
#include <hip/hip_runtime.h>
#include <stdint.h>

// Problem constants
#define N_ROWS 8192
#define D_DIM  1024
#define M_CENT 20000
#define M_PAD  20224          // 79 * 256
#define M_TILES 79            // 256-wide center tiles
#define Y_DIM  256
#define BM 64                 // rows of X per block (2 blocks/CU geometry)
#define BN 256                // centers per M-iteration (wave tile 64x64)
#define BK 32                 // K-chunk of D (R12: 64 -> 32, see header comment)
#define NCHUNK 32             // D_DIM / BK
#define MSPLIT 8
#define TILES_PER_SPLIT 10    // ceil(79/8)
#define LDSP_STRIDE 264       // 256 + 8 pad: 33 16B-slots/row == 1 mod 8 -> conflict-free

// LDS layout (u16 element offsets into lds_all), R12:
//   buf0: [0, 10240)        = X[64][32] (2048) + Z[256][32] (8192)
//   buf1: [10240, 20480)    = same, second stage buffer
//   p   : [20480, 37376)    = P[64][264] (16896) -- FULLY DISJOINT from bufs
// + dedicated lds_xsq[64] (256 B) + lds_zsq[256] (1 KB).
// Total 76032 B < 81920 -> 2 blocks/CU preserved, AND norms live in LDS
// (the only register shape that has ever run spill-free: R2/R10).
#define BUFE 10240            // elements per stage buffer
#define ZOFFE 2048            // Z offset within a buffer
#define POFF 20480            // p region start

typedef __attribute__((ext_vector_type(4))) float  f32x4;
typedef __attribute__((ext_vector_type(8))) __bf16 bf16x8;

__device__ __forceinline__ unsigned short f2bf(float f) {
    union { float f; unsigned u; } v; v.f = f;
    unsigned u = v.u;
    u += 0x7FFFu + ((u >> 16) & 1u);   // RNE
    return (unsigned short)(u >> 16);
}

// async global->LDS, 16B per lane. LDS dest must be wave-uniform base + lane*16.
__device__ __forceinline__ void gll16(void* lds, const void* g) {
    __builtin_amdgcn_global_load_lds(
        (const __attribute__((address_space(1))) void*)g,
        (__attribute__((address_space(3))) void*)lds, 16, 0, 0);
}

// cast fp32 rows -> bf16, compute fp32 row sum-of-squares; pad rows -> zeros
__global__ void cast_rows_kernel(const float* __restrict__ src,
                                 unsigned short* __restrict__ dst,
                                 float* __restrict__ sq, int nrows_valid) {
    int row = blockIdx.x;
    int t = threadIdx.x;  // 256 threads, 4 floats each = 1024 = D_DIM
    float s = 0.f;
    if (row < nrows_valid) {
        float4 v = ((const float4*)(src + (size_t)row * D_DIM))[t];
        s = v.x * v.x + v.y * v.y + v.z * v.z + v.w * v.w;
        ushort4 o;
        o.x = f2bf(v.x); o.y = f2bf(v.y); o.z = f2bf(v.z); o.w = f2bf(v.w);
        ((ushort4*)(dst + (size_t)row * D_DIM))[t] = o;
    } else {
        ((ushort4*)(dst + (size_t)row * D_DIM))[t] = make_ushort4(0, 0, 0, 0);
    }
    __shared__ float red[4];
    for (int off = 32; off; off >>= 1) s += __shfl_down(s, off, 64);
    if ((t & 63) == 0) red[t >> 6] = s;
    __syncthreads();
    if (t == 0) sq[row] = red[0] + red[1] + red[2] + red[3];
}

// W [M][Y] fp32 -> WT [Y][M_PAD] bf16, pad rows (centers >= M_CENT) -> 0
__global__ void cast_wT_kernel(const float* __restrict__ w,
                               unsigned short* __restrict__ wT) {
    __shared__ float tile[32][33];
    int k0 = blockIdx.x * 32;   // center dim
    int y0 = blockIdx.y * 32;   // Y dim
    int tx = threadIdx.x & 31;
    int ty = threadIdx.x >> 5;  // 0..7
    #pragma unroll
    for (int i = 0; i < 4; ++i) {
        int k = k0 + ty + i * 8;
        float v = (k < M_CENT) ? w[(size_t)k * Y_DIM + y0 + tx] : 0.f;
        tile[tx][ty + i * 8] = v;     // tile[y_local][k_local]
    }
    __syncthreads();
    #pragma unroll
    for (int i = 0; i < 4; ++i) {
        int yl = ty + i * 8;
        wT[(size_t)(y0 + yl) * M_PAD + k0 + tx] = f2bf(tile[yl][tx]);
    }
}

// ---------------------------------------------------------------------------
// R12 (post-mortems R8-R11: register budget is EXACTLY saturated -- 2 blk/CU
// x 4 waves = 256 unified regs/wave; S(64)+Oacc(64)=128 accum + 128 arch = 0
// headroom.  Every no-spill run (R2/R10) read norms from LDS; every reg-norm
// run (R8) or allocator-steering attempt (R9 LDS-gap, R11 AGPR pins) spilled.
// R7 showed dedicated norm arrays can't fit beside BK=64 double-buffers at
// the exact 81920 cap.  Fix the FIT, not the allocator):
//  - BK=32: bufs 2 x 20480 B; p (33792 B) DISJOINT; dedicated lds_xsq/zsq.
//    Total 76032 B < 81920 -> still 2 blocks/CU.  No aliasing constraints:
//    no phase-1->2 barrier, no tile-parity dance, prefetch always legal.
//  - Register shape == R2/R10's proven no-spill form (norms from LDS,
//    frag transients only).
//  - Counted-vmcnt raw-barrier pipeline kept (HW-verified R6-R8), now
//    vmcnt(5): per chunk barA -> STAGE(next, 5 gll16) -> vmcnt(5) -> barB
//    -> 8 ds_read_b128 -> 16 MFMA.  vmcnt never drains in Phase 1; chunk 31
//    prefetches next tile's chunk 0 into buf0 (lands during Phases 2-3).
//  - Frag-read swizzle: c ^= (row&3) on 16B units (2-way residual, benign).
//  - Cost accepted for measurement: 64 barriers/tile (vs 34), ~300cyc/chunk
//    prefetch slack (vs 600).  Fork: WRITE clean but dur>=600 -> barrier-
//    bound -> next round: BK=64 + split-S half-BN passes.
//  Sentinels: WRITE ~75 MB (spill dead, primary), LDS ~76 KB, VGPR ~128.
// ---------------------------------------------------------------------------

#define STAGE(PAR, M0, KBASE) do {                                            \
    { int lin_ = t; int row_ = lin_ >> 2, c_ = lin_ & 3;   /* X: 256 units */ \
      gll16(&lds_all[(PAR) * BUFE + lin_ * 8],                                \
            Xb + (size_t)(row0 + row_) * D_DIM + (KBASE) +                    \
                ((c_ ^ (row_ & 3)) * 8)); }                                   \
    _Pragma("unroll")                                                         \
    for (int i_ = 0; i_ < 4; ++i_) {          /* Z: 1024 units */             \
        int lin_ = t + i_ * 256;                                              \
        int row_ = lin_ >> 2, c_ = lin_ & 3;                                  \
        gll16(&lds_all[(PAR) * BUFE + ZOFFE + lin_ * 8],                      \
              Zb + (size_t)((M0) + row_) * D_DIM + (KBASE) +                  \
                  ((c_ ^ (row_ & 3)) * 8));                                   \
    } } while (0)

// One K-chunk.  PAR literal 0/1.  On entry: [stage(kc)x5] outstanding
// (issued one chunk earlier); buf[PAR^1]'s readers all passed barA.
// vmcnt(5) keeps the 5 JUST-ISSUED ops outstanding and drains everything
// older (stage(kc) + any stray scalar loads) -- robust counting.
#define CHUNK(PAR, M0N, KBN) do {                                             \
    asm volatile("" ::: "memory");                                            \
    __builtin_amdgcn_s_barrier();          /* barA: buf[PAR^1] free */        \
    asm volatile("" ::: "memory");                                            \
    STAGE(PAR ^ 1, M0N, KBN);                                                 \
    __builtin_amdgcn_sched_barrier(0);                                        \
    asm volatile("s_waitcnt vmcnt(5)" ::: "memory"); /* stage(kc) done */     \
    __builtin_amdgcn_s_barrier();          /* barB: everyone's stage done */  \
    asm volatile("" ::: "memory");                                            \
    bf16x8 a_[4], b_[4];                                                      \
    _Pragma("unroll")                                                         \
    for (int it_ = 0; it_ < 4; ++it_)                                         \
        a_[it_] = *(const bf16x8*)&lds_all[(PAR) * BUFE +                     \
            (it_ * 16 + l16) * BK + swl];                                     \
    _Pragma("unroll")                                                         \
    for (int jt_ = 0; jt_ < 4; ++jt_)                                         \
        b_[jt_] = *(const bf16x8*)&lds_all[(PAR) * BUFE + ZOFFE +             \
            (wave * 64 + jt_ * 16 + l16) * BK + swl];                         \
    __builtin_amdgcn_s_setprio(1);                                            \
    _Pragma("unroll")                                                         \
    for (int it_ = 0; it_ < 4; ++it_)                                         \
        _Pragma("unroll")                                                     \
        for (int jt_ = 0; jt_ < 4; ++jt_)                                     \
            S[it_ * 4 + jt_] = __builtin_amdgcn_mfma_f32_16x16x32_bf16(       \
                a_[it_], b_[jt_], S[it_ * 4 + jt_], 0, 0, 0);                 \
    __builtin_amdgcn_s_setprio(0);                                            \
  } while (0)

__global__ void __launch_bounds__(256, 2)
fused_kernel(const unsigned short* __restrict__ Xb,
             const unsigned short* __restrict__ Zb,
             const unsigned short* __restrict__ WbT,
             const float* __restrict__ xsq,
             const float* __restrict__ zsq,
             const int* __restrict__ bwp,
             float* __restrict__ out) {
    __shared__ unsigned short lds_all[POFF + BM * LDSP_STRIDE];  // 74752 B
    __shared__ float lds_xsq[BM];                                // 256 B
    __shared__ float lds_zsq[BN];                                // 1 KB -> 76032 B

    const int t    = threadIdx.x;
    const int wave = t >> 6;      // 0..3: m-slab (phase1 B, phase3 y-slab)
    const int lane = t & 63;
    const int quad = lane >> 4;
    const int l16  = lane & 15;
    const int swl  = (quad ^ (l16 & 3)) * 8;   // frag-read swizzled k-offset

    const int row0 = blockIdx.x * BM;          // R2 known-good mapping
    const int mt0  = blockIdx.y * TILES_PER_SPLIT;
    int mt_end = mt0 + TILES_PER_SPLIT;
    if (mt_end > M_TILES) mt_end = M_TILES;

    // bandwidth: int32 per harness convention (Python int 10); tolerate float bits too
    int bwi = *bwp;
    float bw;
    if (bwi > 0 && bwi < 1000000) bw = (float)bwi;
    else { union { int i; float f; } u; u.i = bwi; bw = u.f; }
    const float inv_bw = 1.0f / bw;

    if (t < BM) lds_xsq[t] = xsq[row0 + t];    // once per block (R2 pattern)
    asm volatile("s_waitcnt lgkmcnt(0)" ::: "memory");

    const f32x4 vzero = {0.f, 0.f, 0.f, 0.f};
    f32x4 Oacc[16];
    #pragma unroll
    for (int i = 0; i < 16; ++i) Oacc[i] = vzero;

    // prologue: stage (tile mt0, chunk 0) -> buf0
    STAGE(0, mt0 * BN, 0);
    __builtin_amdgcn_sched_barrier(0);

    for (int mt = mt0; mt < mt_end; ++mt) {
        const int m0 = mt * BN;
        // last tile of split prefetches itself (valid mem, unused)
        const int m0next = (mt + 1 < mt_end) ? m0 + BN : m0;

        // zsq -> dedicated LDS at tile top (R2/R10 no-spill pattern).
        // Safe vs other waves: previous tile's only lds_zsq readers are in
        // Phase 2, which precedes the Phase-2->3 barrier every wave passed
        // before I could get here.  Visibility: 64 chunk barriers ahead.
        lds_zsq[t] = zsq[m0 + t];              // BN == blockDim.x == 256
        asm volatile("s_waitcnt lgkmcnt(0)" ::: "memory");

        f32x4 S[16];
        #pragma unroll
        for (int i = 0; i < 16; ++i) S[i] = vzero;

        // -------- Phase 1: S[64x256] = X * Z^T over D, counted-vmcnt pipe --
        // chunk kc reads buf[kc&1]; stages kc+1 into buf[(kc+1)&1].
        // kc=31 stages NEXT TILE's chunk 0 into buf0 (p is disjoint),
        // landing during Phases 2-3 -> no drain at tile boundary.
        #pragma unroll 1
        for (int kc = 0; kc < NCHUNK; kc += 2) {
            const bool last = (kc + 2 == NCHUNK);
            CHUNK(0, m0, (kc + 1) * BK);
            CHUNK(1, last ? m0next : m0, last ? 0 : (kc + 2) * BK);
        }
        // no phase-1->2 barrier: p, lds norms, and S are all disjoint from
        // the bufs; the in-flight buf0 prefetch is disjoint from p.

        // -------- Phase 2: P = exp(-sqrt(d2)/bw) -> p (bf16) --------
        #pragma unroll
        for (int it = 0; it < 4; ++it) {
            #pragma unroll
            for (int jt = 0; jt < 4; ++jt) {
                f32x4 s4 = S[it * 4 + jt];
                const int col = wave * 64 + jt * 16 + l16;
                const float zq = lds_zsq[col];
                #pragma unroll
                for (int r = 0; r < 4; ++r) {
                    const int row = it * 16 + quad * 4 + r;   // C-layout
                    float d2 = lds_xsq[row] + zq - 2.0f * s4[r];
                    d2 = fmaxf(d2, 0.f);
                    float d;
                    asm("v_sqrt_f32 %0, %1" : "=v"(d) : "v"(d2));
                    float p = __expf(-d * inv_bw);
                    lds_all[POFF + row * LDSP_STRIDE + col] = f2bf(p);
                }
            }
        }
        // P-write -> P-read: LDS-only drain; buf0 prefetch stays in flight
        asm volatile("s_waitcnt lgkmcnt(0)" ::: "memory");
        __builtin_amdgcn_s_barrier();
        asm volatile("" ::: "memory");

        // -------- Phase 3: O += P[64x256] * Wtile[256x256] --------
        #pragma unroll
        for (int ks = 0; ks < 8; ++ks) {
            const int koff = ks * 32 + quad * 8;
            bf16x8 a[4], b[4];
            #pragma unroll
            for (int rt = 0; rt < 4; ++rt)
                a[rt] = *(const bf16x8*)&lds_all[POFF +
                    (rt * 16 + l16) * LDSP_STRIDE + koff];
            #pragma unroll
            for (int ct = 0; ct < 4; ++ct) {
                const int y = wave * 64 + ct * 16 + l16;
                b[ct] = *(const bf16x8*)(WbT + (size_t)y * M_PAD + m0 + koff);
            }
            __builtin_amdgcn_s_setprio(1);
            #pragma unroll
            for (int rt = 0; rt < 4; ++rt)
                #pragma unroll
                for (int ct = 0; ct < 4; ++ct)
                    Oacc[rt * 4 + ct] = __builtin_amdgcn_mfma_f32_16x16x32_bf16(
                        a[rt], b[ct], Oacc[rt * 4 + ct], 0, 0, 0);
            __builtin_amdgcn_s_setprio(0);
        }
        // next tile's CHUNK(0) barA separates these p reads from nothing --
        // p is only rewritten in next Phase 2, 64 chunk-barriers away.
        // W-loads all retire within Phase 3 (consumed), so the next chunk's
        // vmcnt(5) still counts only the stage + prefetch ops.
    }

    // drain the dangling last-tile prefetch before LDS is released
    asm volatile("s_waitcnt vmcnt(0)" ::: "memory");

    // -------- epilogue: accumulate M-splits via device-scope fp32 atomics ----
    #pragma unroll
    for (int rt = 0; rt < 4; ++rt) {
        #pragma unroll
        for (int ct = 0; ct < 4; ++ct) {
            f32x4 v = Oacc[rt * 4 + ct];
            const int y = wave * 64 + ct * 16 + l16;
            #pragma unroll
            for (int r = 0; r < 4; ++r) {
                const int row = row0 + rt * 16 + quad * 4 + r;
                atomicAdd(&out[(size_t)row * Y_DIM + y], v[r]);
            }
        }
    }
}

extern "C" void kernel_launch(void* const* d_in, const int* in_sizes, int n_in,
                              void* d_out, int out_size, void* d_ws, size_t ws_size,
                              hipStream_t stream) {
    const float* X = (const float*)d_in[0];
    const float* Z = (const float*)d_in[1];
    const float* W = (const float*)d_in[2];
    const int*  bw = (const int*)d_in[3];
    float* out = (float*)d_out;

    char* ws = (char*)d_ws;
    size_t off = 0;
    unsigned short* Xb  = (unsigned short*)(ws + off); off += (size_t)N_ROWS * D_DIM * 2;
    unsigned short* Zb  = (unsigned short*)(ws + off); off += (size_t)M_PAD * D_DIM * 2;
    unsigned short* WbT = (unsigned short*)(ws + off); off += (size_t)Y_DIM * M_PAD * 2;
    float* xsq = (float*)(ws + off); off += (size_t)N_ROWS * 4;
    float* zsq = (float*)(ws + off); off += (size_t)M_PAD * 4;
    // total ws use: ~68.7 MB

    hipMemsetAsync(d_out, 0, (size_t)out_size * sizeof(float), stream);
    cast_rows_kernel<<<N_ROWS, 256, 0, stream>>>(X, Xb, xsq, N_ROWS);
    cast_rows_kernel<<<M_PAD, 256, 0, stream>>>(Z, Zb, zsq, M_CENT);
    cast_wT_kernel<<<dim3(M_PAD / 32, Y_DIM / 32), 256, 0, stream>>>(W, WbT);
    fused_kernel<<<dim3(N_ROWS / BM, MSPLIT), 256, 0, stream>>>(
        Xb, Zb, WbT, xsq, zsq, bw, out);
}

// Round 11
// 774.661 us; speedup vs baseline: 1.2688x; 1.0113x over previous
//
#include <hip/hip_runtime.h>
#include <stdint.h>

// Problem constants
#define N_ROWS 8192
#define D_DIM  1024
#define M_CENT 20000
#define M_PAD  20224          // 79 * 256
#define M_TILES 79            // 256-wide center tiles
#define Y_DIM  256
#define BM 64                 // rows of X per block (2 blocks/CU geometry)
#define BN 256                // centers per M-iteration (wave tile 64x64)
#define BK 32                 // K-chunk of D
#define NCHUNK 32             // D_DIM / BK
#define MSPLIT 8
#define TILES_PER_SPLIT 10    // ceil(79/8)
#define LDSP_STRIDE 264       // 256 + 8 pad: 33 16B-slots/row == 1 mod 8 -> conflict-free

// LDS layout (u16 element offsets into lds_all), as R12 (HW-verified no-spill):
//   buf0: [0, 10240)        = X[64][32] (2048) + Z[256][32] (8192)
//   buf1: [10240, 20480)    = same, second stage buffer
//   p   : [20480, 37376)    = P[64][264] (16896) -- FULLY DISJOINT from bufs
// + dedicated lds_xsq[64] (256 B) + lds_zsq[256] (1 KB).
// Total 76032 B < 81920 -> 2 blocks/CU preserved, norms in LDS (no spill).
#define BUFE 10240            // elements per stage buffer
#define ZOFFE 2048            // Z offset within a buffer
#define POFF 20480            // p region start

typedef __attribute__((ext_vector_type(4))) float  f32x4;
typedef __attribute__((ext_vector_type(8))) __bf16 bf16x8;

__device__ __forceinline__ unsigned short f2bf(float f) {
    union { float f; unsigned u; } v; v.f = f;
    unsigned u = v.u;
    u += 0x7FFFu + ((u >> 16) & 1u);   // RNE
    return (unsigned short)(u >> 16);
}

// async global->LDS, 16B per lane. LDS dest must be wave-uniform base + lane*16.
__device__ __forceinline__ void gll16(void* lds, const void* g) {
    __builtin_amdgcn_global_load_lds(
        (const __attribute__((address_space(1))) void*)g,
        (__attribute__((address_space(3))) void*)lds, 16, 0, 0);
}

// cast fp32 rows -> bf16, compute fp32 row sum-of-squares; pad rows -> zeros
__global__ void cast_rows_kernel(const float* __restrict__ src,
                                 unsigned short* __restrict__ dst,
                                 float* __restrict__ sq, int nrows_valid) {
    int row = blockIdx.x;
    int t = threadIdx.x;  // 256 threads, 4 floats each = 1024 = D_DIM
    float s = 0.f;
    if (row < nrows_valid) {
        float4 v = ((const float4*)(src + (size_t)row * D_DIM))[t];
        s = v.x * v.x + v.y * v.y + v.z * v.z + v.w * v.w;
        ushort4 o;
        o.x = f2bf(v.x); o.y = f2bf(v.y); o.z = f2bf(v.z); o.w = f2bf(v.w);
        ((ushort4*)(dst + (size_t)row * D_DIM))[t] = o;
    } else {
        ((ushort4*)(dst + (size_t)row * D_DIM))[t] = make_ushort4(0, 0, 0, 0);
    }
    __shared__ float red[4];
    for (int off = 32; off; off >>= 1) s += __shfl_down(s, off, 64);
    if ((t & 63) == 0) red[t >> 6] = s;
    __syncthreads();
    if (t == 0) sq[row] = red[0] + red[1] + red[2] + red[3];
}

// W [M][Y] fp32 -> WT [Y][M_PAD] bf16, pad rows (centers >= M_CENT) -> 0
__global__ void cast_wT_kernel(const float* __restrict__ w,
                               unsigned short* __restrict__ wT) {
    __shared__ float tile[32][33];
    int k0 = blockIdx.x * 32;   // center dim
    int y0 = blockIdx.y * 32;   // Y dim
    int tx = threadIdx.x & 31;
    int ty = threadIdx.x >> 5;  // 0..7
    #pragma unroll
    for (int i = 0; i < 4; ++i) {
        int k = k0 + ty + i * 8;
        float v = (k < M_CENT) ? w[(size_t)k * Y_DIM + y0 + tx] : 0.f;
        tile[tx][ty + i * 8] = v;     // tile[y_local][k_local]
    }
    __syncthreads();
    #pragma unroll
    for (int i = 0; i < 4; ++i) {
        int yl = ty + i * 8;
        wT[(size_t)(y0 + yl) * M_PAD + k0 + tx] = f2bf(tile[yl][tx]);
    }
}

// ---------------------------------------------------------------------------
// R13 = R12 with ONE change (R12 post-mortem: spill DEAD -- WRITE 68.6MB --
// but SQ_LDS_BANK_CONFLICT 5.2M -> 46.6M.  Mechanism: BK=32 row = 64B = 16
// banks; swizzle c^(row&3) is degenerate because row&3's low bit IS the
// bank-start's row-parity bit -> within a quarter-wave only 4 distinct
// 4-bank groups, 4 lanes each w/ distinct addrs = 4-way conflict on every
// Phase-1 ds_read_b128 (41M extra cyc / 10.5M reads = 4 cyc/read = m136's
// 1.58x for 4-way).  R8's BK=64 c^(row&7) gave 8 groups x 2 lanes = free):
//  - Swizzle f(row) = (row>>1)&3 (row bits 1..2; bank_start then uses row
//    bits 0..2 jointly): quarter-wave = 8 distinct bank-groups x 2 lanes,
//    the pair (l16, l16+8) differs by 512B = 0 mod 32 banks -> 2-way = FREE.
//    Reads: swl = (quad ^ ((l16>>1)&3))*8, uniform for a_ and b_ (it*8,
//    jt*8, wave*32 all = 0 mod 4).  Staging pre-swizzles the same involution
//    on the global source column (both-sides-or-neither, rule #21).
//  - Everything else byte-identical to R12 (clean A/B): counted-vmcnt
//    raw-barrier pipeline (vmcnt(5)), disjoint p, LDS norms, BM=64,
//    MSPLIT=8, 2 blocks/CU, launch_bounds(256,2).
//  Sentinels: SQ_LDS_BANK_CONFLICT ~5-7M (primary mechanism check);
//  WRITE ~68MB unchanged.  Fork: conflicts drop but dur ~680 -> conflict
//  cycles were latency-hidden -> chain is barrier/L2-latency-bound -> next
//  round cuts barrier frequency.
// ---------------------------------------------------------------------------

#define STAGE(PAR, M0, KBASE) do {                                            \
    { int lin_ = t; int row_ = lin_ >> 2, c_ = lin_ & 3;   /* X: 256 units */ \
      gll16(&lds_all[(PAR) * BUFE + lin_ * 8],                                \
            Xb + (size_t)(row0 + row_) * D_DIM + (KBASE) +                    \
                ((c_ ^ ((row_ >> 1) & 3)) * 8)); }                            \
    _Pragma("unroll")                                                         \
    for (int i_ = 0; i_ < 4; ++i_) {          /* Z: 1024 units */             \
        int lin_ = t + i_ * 256;                                              \
        int row_ = lin_ >> 2, c_ = lin_ & 3;                                  \
        gll16(&lds_all[(PAR) * BUFE + ZOFFE + lin_ * 8],                      \
              Zb + (size_t)((M0) + row_) * D_DIM + (KBASE) +                  \
                  ((c_ ^ ((row_ >> 1) & 3)) * 8));                            \
    } } while (0)

// One K-chunk.  PAR literal 0/1.  On entry: [stage(kc)x5] outstanding
// (issued one chunk earlier); buf[PAR^1]'s readers all passed barA.
// vmcnt(5) keeps the 5 JUST-ISSUED ops outstanding and drains everything
// older (stage(kc) + any stray scalar loads) -- robust counting.
#define CHUNK(PAR, M0N, KBN) do {                                             \
    asm volatile("" ::: "memory");                                            \
    __builtin_amdgcn_s_barrier();          /* barA: buf[PAR^1] free */        \
    asm volatile("" ::: "memory");                                            \
    STAGE(PAR ^ 1, M0N, KBN);                                                 \
    __builtin_amdgcn_sched_barrier(0);                                        \
    asm volatile("s_waitcnt vmcnt(5)" ::: "memory"); /* stage(kc) done */     \
    __builtin_amdgcn_s_barrier();          /* barB: everyone's stage done */  \
    asm volatile("" ::: "memory");                                            \
    bf16x8 a_[4], b_[4];                                                      \
    _Pragma("unroll")                                                         \
    for (int it_ = 0; it_ < 4; ++it_)                                         \
        a_[it_] = *(const bf16x8*)&lds_all[(PAR) * BUFE +                     \
            (it_ * 16 + l16) * BK + swl];                                     \
    _Pragma("unroll")                                                         \
    for (int jt_ = 0; jt_ < 4; ++jt_)                                         \
        b_[jt_] = *(const bf16x8*)&lds_all[(PAR) * BUFE + ZOFFE +             \
            (wave * 64 + jt_ * 16 + l16) * BK + swl];                         \
    __builtin_amdgcn_s_setprio(1);                                            \
    _Pragma("unroll")                                                         \
    for (int it_ = 0; it_ < 4; ++it_)                                         \
        _Pragma("unroll")                                                     \
        for (int jt_ = 0; jt_ < 4; ++jt_)                                     \
            S[it_ * 4 + jt_] = __builtin_amdgcn_mfma_f32_16x16x32_bf16(       \
                a_[it_], b_[jt_], S[it_ * 4 + jt_], 0, 0, 0);                 \
    __builtin_amdgcn_s_setprio(0);                                            \
  } while (0)

__global__ void __launch_bounds__(256, 2)
fused_kernel(const unsigned short* __restrict__ Xb,
             const unsigned short* __restrict__ Zb,
             const unsigned short* __restrict__ WbT,
             const float* __restrict__ xsq,
             const float* __restrict__ zsq,
             const int* __restrict__ bwp,
             float* __restrict__ out) {
    __shared__ unsigned short lds_all[POFF + BM * LDSP_STRIDE];  // 74752 B
    __shared__ float lds_xsq[BM];                                // 256 B
    __shared__ float lds_zsq[BN];                                // 1 KB -> 76032 B

    const int t    = threadIdx.x;
    const int wave = t >> 6;      // 0..3: m-slab (phase1 B, phase3 y-slab)
    const int lane = t & 63;
    const int quad = lane >> 4;
    const int l16  = lane & 15;
    const int swl  = (quad ^ ((l16 >> 1) & 3)) * 8;  // R13 fixed swizzle

    const int row0 = blockIdx.x * BM;          // R2 known-good mapping
    const int mt0  = blockIdx.y * TILES_PER_SPLIT;
    int mt_end = mt0 + TILES_PER_SPLIT;
    if (mt_end > M_TILES) mt_end = M_TILES;

    // bandwidth: int32 per harness convention (Python int 10); tolerate float bits too
    int bwi = *bwp;
    float bw;
    if (bwi > 0 && bwi < 1000000) bw = (float)bwi;
    else { union { int i; float f; } u; u.i = bwi; bw = u.f; }
    const float inv_bw = 1.0f / bw;

    if (t < BM) lds_xsq[t] = xsq[row0 + t];    // once per block (R2 pattern)
    asm volatile("s_waitcnt lgkmcnt(0)" ::: "memory");

    const f32x4 vzero = {0.f, 0.f, 0.f, 0.f};
    f32x4 Oacc[16];
    #pragma unroll
    for (int i = 0; i < 16; ++i) Oacc[i] = vzero;

    // prologue: stage (tile mt0, chunk 0) -> buf0
    STAGE(0, mt0 * BN, 0);
    __builtin_amdgcn_sched_barrier(0);

    for (int mt = mt0; mt < mt_end; ++mt) {
        const int m0 = mt * BN;
        // last tile of split prefetches itself (valid mem, unused)
        const int m0next = (mt + 1 < mt_end) ? m0 + BN : m0;

        // zsq -> dedicated LDS at tile top (R2/R10 no-spill pattern).
        lds_zsq[t] = zsq[m0 + t];              // BN == blockDim.x == 256
        asm volatile("s_waitcnt lgkmcnt(0)" ::: "memory");

        f32x4 S[16];
        #pragma unroll
        for (int i = 0; i < 16; ++i) S[i] = vzero;

        // -------- Phase 1: S[64x256] = X * Z^T over D, counted-vmcnt pipe --
        // chunk kc reads buf[kc&1]; stages kc+1 into buf[(kc+1)&1].
        // kc=31 stages NEXT TILE's chunk 0 into buf0 (p is disjoint),
        // landing during Phases 2-3 -> no drain at tile boundary.
        #pragma unroll 1
        for (int kc = 0; kc < NCHUNK; kc += 2) {
            const bool last = (kc + 2 == NCHUNK);
            CHUNK(0, m0, (kc + 1) * BK);
            CHUNK(1, last ? m0next : m0, last ? 0 : (kc + 2) * BK);
        }
        // no phase-1->2 barrier: p, lds norms, and S are all disjoint from
        // the bufs; the in-flight buf0 prefetch is disjoint from p.

        // -------- Phase 2: P = exp(-sqrt(d2)/bw) -> p (bf16) --------
        #pragma unroll
        for (int it = 0; it < 4; ++it) {
            #pragma unroll
            for (int jt = 0; jt < 4; ++jt) {
                f32x4 s4 = S[it * 4 + jt];
                const int col = wave * 64 + jt * 16 + l16;
                const float zq = lds_zsq[col];
                #pragma unroll
                for (int r = 0; r < 4; ++r) {
                    const int row = it * 16 + quad * 4 + r;   // C-layout
                    float d2 = lds_xsq[row] + zq - 2.0f * s4[r];
                    d2 = fmaxf(d2, 0.f);
                    float d;
                    asm("v_sqrt_f32 %0, %1" : "=v"(d) : "v"(d2));
                    float p = __expf(-d * inv_bw);
                    lds_all[POFF + row * LDSP_STRIDE + col] = f2bf(p);
                }
            }
        }
        // P-write -> P-read: LDS-only drain; buf0 prefetch stays in flight
        asm volatile("s_waitcnt lgkmcnt(0)" ::: "memory");
        __builtin_amdgcn_s_barrier();
        asm volatile("" ::: "memory");

        // -------- Phase 3: O += P[64x256] * Wtile[256x256] --------
        #pragma unroll
        for (int ks = 0; ks < 8; ++ks) {
            const int koff = ks * 32 + quad * 8;
            bf16x8 a[4], b[4];
            #pragma unroll
            for (int rt = 0; rt < 4; ++rt)
                a[rt] = *(const bf16x8*)&lds_all[POFF +
                    (rt * 16 + l16) * LDSP_STRIDE + koff];
            #pragma unroll
            for (int ct = 0; ct < 4; ++ct) {
                const int y = wave * 64 + ct * 16 + l16;
                b[ct] = *(const bf16x8*)(WbT + (size_t)y * M_PAD + m0 + koff);
            }
            __builtin_amdgcn_s_setprio(1);
            #pragma unroll
            for (int rt = 0; rt < 4; ++rt)
                #pragma unroll
                for (int ct = 0; ct < 4; ++ct)
                    Oacc[rt * 4 + ct] = __builtin_amdgcn_mfma_f32_16x16x32_bf16(
                        a[rt], b[ct], Oacc[rt * 4 + ct], 0, 0, 0);
            __builtin_amdgcn_s_setprio(0);
        }
        // next tile's CHUNK(0) barA separates these p reads from nothing --
        // p is only rewritten in next Phase 2, 64 chunk-barriers away.
    }

    // drain the dangling last-tile prefetch before LDS is released
    asm volatile("s_waitcnt vmcnt(0)" ::: "memory");

    // -------- epilogue: accumulate M-splits via device-scope fp32 atomics ----
    #pragma unroll
    for (int rt = 0; rt < 4; ++rt) {
        #pragma unroll
        for (int ct = 0; ct < 4; ++ct) {
            f32x4 v = Oacc[rt * 4 + ct];
            const int y = wave * 64 + ct * 16 + l16;
            #pragma unroll
            for (int r = 0; r < 4; ++r) {
                const int row = row0 + rt * 16 + quad * 4 + r;
                atomicAdd(&out[(size_t)row * Y_DIM + y], v[r]);
            }
        }
    }
}

extern "C" void kernel_launch(void* const* d_in, const int* in_sizes, int n_in,
                              void* d_out, int out_size, void* d_ws, size_t ws_size,
                              hipStream_t stream) {
    const float* X = (const float*)d_in[0];
    const float* Z = (const float*)d_in[1];
    const float* W = (const float*)d_in[2];
    const int*  bw = (const int*)d_in[3];
    float* out = (float*)d_out;

    char* ws = (char*)d_ws;
    size_t off = 0;
    unsigned short* Xb  = (unsigned short*)(ws + off); off += (size_t)N_ROWS * D_DIM * 2;
    unsigned short* Zb  = (unsigned short*)(ws + off); off += (size_t)M_PAD * D_DIM * 2;
    unsigned short* WbT = (unsigned short*)(ws + off); off += (size_t)Y_DIM * M_PAD * 2;
    float* xsq = (float*)(ws + off); off += (size_t)N_ROWS * 4;
    float* zsq = (float*)(ws + off); off += (size_t)M_PAD * 4;
    // total ws use: ~68.7 MB

    hipMemsetAsync(d_out, 0, (size_t)out_size * sizeof(float), stream);
    cast_rows_kernel<<<N_ROWS, 256, 0, stream>>>(X, Xb, xsq, N_ROWS);
    cast_rows_kernel<<<M_PAD, 256, 0, stream>>>(Z, Zb, zsq, M_CENT);
    cast_wT_kernel<<<dim3(M_PAD / 32, Y_DIM / 32), 256, 0, stream>>>(W, WbT);
    fused_kernel<<<dim3(N_ROWS / BM, MSPLIT), 256, 0, stream>>>(
        Xb, Zb, WbT, xsq, zsq, bw, out);
}